// Round 9
// baseline (1501.890 us; speedup 1.0000x reference)
//
#include <hip/hip_runtime.h>
#include <hip/hip_bf16.h>

// R9: (a) CRASH FIX -- R8's error-checked launch ladder is illegal under graph
// capture (a failed hipLaunchCooperativeKernel invalidates the capture; the
// fallback then fails too -> harness exception). Revert to the ONE launch
// configuration proven to pass and perform (R6: NPART=2, 256 blocks, (512,1),
// 951us), launched unconditionally. (b) the experiment: manual double-buffered
// PREFETCH in the phase loop. Counters say the stall is HBM latency on the
// scattered oth reads (1.1GB traffic at 14% BW, VALUBusy 40%, 2 waves/SIMD);
// the ~1500-cycle compute body can hide the ~900-cycle latency if problem
// p+1's loads are issued during problem p's compute. Explicit A/B register
// buffers + 2x-unrolled body (no runtime indexing -> no scratch). +16 VGPR,
// benign at 1 block/CU (2 waves/SIMD needs only VGPR<=256). Numerics: same
// values, same order -> absmax stays 0.
#define BDIM 512
#define NBAT 128
#define SS   48
#define DD   8
#define HDIM 8
#define NL   8
#define NC   7
#define NWAV 8
#define PIX  (SS*SS)
#define RGN  (PIX*DD)            // one region: 18432 floats
#define GBAT (2*RGN)             // row+col regions per batch
#define BUFSZ ((size_t)NBAT*GBAT)      // one parity buffer (floats)
#define KVV  384
#define KVW  768
#define KVTOT (NWAV*KVW)
#define SMEMF_FLOATS (KVTOT + 264 + 784 + 8)
#define SMEMF_BYTES  (SMEMF_FLOATS*4)        // 28,800 B
#define FLAGS_OFF ((size_t)2*BUFSZ)          // float offset of flags in d_ws

__device__ __forceinline__ float ldsel(const void* p, long i, bool bf) {
    return bf ? __bfloat162float(((const __hip_bfloat16*)p)[i])
              : ((const float*)p)[i];
}

__device__ __forceinline__ void flag_post(unsigned* f, unsigned v) {
    __threadfence();                                   // release: drain + L2 wb
    __hip_atomic_store(f, v, __ATOMIC_RELAXED, __HIP_MEMORY_SCOPE_AGENT);
}
__device__ __forceinline__ void flag_wait(unsigned* f, unsigned v) {
    while (__hip_atomic_load(f, __ATOMIC_RELAXED, __HIP_MEMORY_SCOPE_AGENT) < v)
        __builtin_amdgcn_s_sleep(1);
}

// One problem's full attention body. Inputs arrive as already-loaded register
// float4s (own o0f/o1f; opposite t0f/t1f) so the caller can prefetch the next
// problem's loads behind this compute. FIRST=1: layer 0 (h0 as-is, no relu-add).
template <int FIRST>
__device__ __forceinline__
void attn_body(int prob, const float4 o0f, const float4 o1f,
               const float4 t0f, const float4 t1f,
               float4* __restrict__ gout, float* __restrict__ kvw,
               const float* __restrict__ wb, int lane, int tl)
{
    const float4* kv4 = reinterpret_cast<const float4*>(kvw);

    float ht[DD];
    if (FIRST) {
        ht[0]=o0f.x; ht[1]=o0f.y; ht[2]=o0f.z; ht[3]=o0f.w;
        ht[4]=o1f.x; ht[5]=o1f.y; ht[6]=o1f.z; ht[7]=o1f.w;
    } else {
        ht[0]=fmaxf(0.f,o0f.x+t0f.x); ht[1]=fmaxf(0.f,o0f.y+t0f.y);
        ht[2]=fmaxf(0.f,o0f.z+t0f.z); ht[3]=fmaxf(0.f,o0f.w+t0f.w);
        ht[4]=fmaxf(0.f,o1f.x+t1f.x); ht[5]=fmaxf(0.f,o1f.y+t1f.y);
        ht[6]=fmaxf(0.f,o1f.z+t1f.z); ht[7]=fmaxf(0.f,o1f.w+t1f.w);
    }

    // q/k/v projections; fold 0.5 (E^-0.5) * log2(e) into q for exp2.
    float q[HDIM];
    {
        float kk[HDIM], vv[HDIM];
        #pragma unroll
        for (int o = 0; o < HDIM; ++o) {
            float aq = 0.f, ak = 0.f, av = 0.f;
            #pragma unroll
            for (int d = 0; d < DD; ++d) {
                aq += ht[d] * wb[o*8 + d];
                ak += ht[d] * wb[64 + o*8 + d];
                av += ht[d] * wb[128 + o*8 + d];
            }
            q[o] = aq * 0.72134752044f;  // 0.5 * log2(e)
            kk[o] = ak; vv[o] = av;
        }
        if (lane < SS) {   // lanes 48-63 would duplicate token 47: skip
            float4* kp = reinterpret_cast<float4*>(kvw + tl*8);
            kp[0] = make_float4(kk[0], kk[1], kk[2], kk[3]);
            kp[1] = make_float4(kk[4], kk[5], kk[6], kk[7]);
            float4* vp = reinterpret_cast<float4*>(kvw + KVV + tl*8);
            vp[0] = make_float4(vv[0], vv[1], vv[2], vv[3]);
            vp[1] = make_float4(vv[4], vv[5], vv[6], vv[7]);
        }
    }

    float ov[HDIM];
    #pragma unroll
    for (int hh = 0; hh < 2; ++hh) {
        float dt[SS];
        #pragma unroll
        for (int j2 = 0; j2 < SS; ++j2) {
            const float4 kk4 = kv4[j2*2 + hh];       // LDS same-addr broadcast
            float acc =  q[hh*4+0] * kk4.x;
            acc       += q[hh*4+1] * kk4.y;
            acc       += q[hh*4+2] * kk4.z;
            acc       += q[hh*4+3] * kk4.w;
            dt[j2] = acc;
        }
        // max tree (fmax exactly associative -> bitwise same as chain)
        float mt[24];
        #pragma unroll
        for (int t2 = 0; t2 < 24; ++t2) mt[t2] = fmaxf(dt[t2], dt[t2+24]);
        #pragma unroll
        for (int t2 = 0; t2 < 12; ++t2) mt[t2] = fmaxf(mt[t2], mt[t2+12]);
        #pragma unroll
        for (int t2 = 0; t2 < 6; ++t2)  mt[t2] = fmaxf(mt[t2], mt[t2+6]);
        #pragma unroll
        for (int t2 = 0; t2 < 3; ++t2)  mt[t2] = fmaxf(mt[t2], mt[t2+3]);
        const float m = fmaxf(fmaxf(mt[0], mt[1]), mt[2]);
        float s = 0.f;
        #pragma unroll
        for (int j2 = 0; j2 < SS; ++j2) {
            float pv = exp2f(dt[j2] - m);
            dt[j2] = pv; s += pv;
        }
        float o0 = 0.f, o1 = 0.f, o2 = 0.f, o3 = 0.f;
        #pragma unroll
        for (int j2 = 0; j2 < SS; ++j2) {
            const float4 vv4 = kv4[KVV/4 + j2*2 + hh];
            const float pv = dt[j2];
            o0 += pv * vv4.x;
            o1 += pv * vv4.y;
            o2 += pv * vv4.z;
            o3 += pv * vv4.w;
        }
        float rs = 1.f / s;
        ov[hh*4+0] = o0*rs; ov[hh*4+1] = o1*rs;
        ov[hh*4+2] = o2*rs; ov[hh*4+3] = o3*rs;
    }

    if (lane < SS) {
        float o8[DD];
        #pragma unroll
        for (int d = 0; d < DD; ++d) {
            float acc = wb[256 + d];
            #pragma unroll
            for (int o2 = 0; o2 < HDIM; ++o2) acc += ov[o2] * wb[192 + d*8 + o2];
            o8[d] = acc;
        }
        const int aown = (prob*SS + tl)*2;
        gout[aown]   = make_float4(o8[0], o8[1], o8[2], o8[3]);
        gout[aown+1] = make_float4(o8[4], o8[5], o8[6], o8[7]);
    }
}

// Phase over this wave's 6 problems with double-buffered prefetch: while
// problem p computes (>=1500 cyc of VALU), problem p+1's 4 global loads
// (~900 cyc HBM latency on the scattered oth pair) are in flight.
template <int FIRST>
__device__ __attribute__((noinline))
void attn_phase_f(const float4* __restrict__ gown, const float4* __restrict__ goth,
                  float4* __restrict__ gout, float* __restrict__ kvw,
                  const float* __restrict__ wb, int wav, int lane, int tl)
{
    float4 A0, A1, AT0, AT1;     // buffer A (own pair + oth pair)
    float4 B0, B1, BT0, BT1;     // buffer B
    AT0 = AT1 = BT0 = BT1 = make_float4(0.f, 0.f, 0.f, 0.f);
    {
        const int a = (wav*SS + tl)*2;
        A0 = gown[a]; A1 = gown[a+1];
        if (!FIRST) { const int b = (tl*SS + wav)*2; AT0 = goth[b]; AT1 = goth[b+1]; }
    }
    #pragma unroll 1
    for (int k = 0; k < 3; ++k) {
        const int p0 = wav + (2*k)*NWAV;
        const int p1 = p0 + NWAV;
        {   // prefetch p1 into B (issued; consumed after p0's body)
            const int a = (p1*SS + tl)*2;
            B0 = gown[a]; B1 = gown[a+1];
            if (!FIRST) { const int b = (tl*SS + p1)*2; BT0 = goth[b]; BT1 = goth[b+1]; }
        }
        attn_body<FIRST>(p0, A0, A1, AT0, AT1, gout, kvw, wb, lane, tl);
        if (k < 2) {   // prefetch p0 of next k into A (behind p1's body)
            const int p2 = p1 + NWAV;
            const int a = (p2*SS + tl)*2;
            A0 = gown[a]; A1 = gown[a+1];
            if (!FIRST) { const int b = (tl*SS + p2)*2; AT0 = goth[b]; AT1 = goth[b+1]; }
        }
        attn_body<FIRST>(p1, B0, B1, BT0, BT1, gout, kvw, wb, lane, tl);
    }
}

__global__ void __launch_bounds__(BDIM, 1)   // the one register-safe shape
axial_u(const void* xv, const void* enc_wv, const void* enc_bv,
        const void* pos_rowv, const void* pos_colv,
        const void* Wqv, const void* Wkv, const void* Wvv, const void* Wov,
        const void* bov, const void* cls_wv, const void* cls_bv,
        void* outv, void* wsv)
{
    // dtype sniff on x (wave-uniform): low bits of each dword are a plausible
    // bf16 exponent iff data is bf16-packed; random mantissa bits if fp32.
    const unsigned* xu = (const unsigned*)xv;
    int cnt = 0;
    #pragma unroll
    for (int t = 0; t < 32; ++t) {
        const unsigned w = xu[t];
        const int e = (w >> 7) & 0xff;
        cnt += (e > 100 && e < 150) ? 1 : 0;
    }
    const bool isbf = (cnt >= 20);

    float*    G     = (float*)wsv;
    unsigned* flags = (unsigned*)(G + FLAGS_OFF);

    extern __shared__ float smem[];
    float* kv = smem;              // per-wave k/v scratch [KVTOT]
    float* wb = kv + KVTOT;        // layer weights (own axis) [264]
    float* eb = wb + 264;          // enc params [784]
    float* cb = eb + 784;          // classifier logits [8]

    const int bid   = blockIdx.x;
    const int batch = bid & (NBAT-1);
    const int axis  = bid >> 7;            // 0: row attention, 1: col attention
    const int tid   = threadIdx.x;
    const int lane  = tid & 63;
    const int wav   = tid >> 6;
    const int tl    = lane < SS ? lane : SS-1;
    float* kvw = kv + wav*KVW;

    float* b0 = G + (size_t)batch*GBAT;                 // parity-0 buffer
    float* b1 = G + BUFSZ + (size_t)batch*GBAT;         // parity-1 buffer
    float4* row0 = (float4*)b0;  float4* col0 = (float4*)(b0 + RGN);
    float4* row1 = (float4*)b1;  float4* col1 = (float4*)(b1 + RGN);

    // stage encoder/pos params
    for (int f = tid; f < 784; f += BDIM) {
        float v;
        if (f < 8)        v = ldsel(enc_wv, f, isbf);
        else if (f < 16)  v = ldsel(enc_bv, f-8, isbf);
        else if (f < 400) v = ldsel(pos_rowv, f-16, isbf);
        else              v = ldsel(pos_colv, f-400, isbf);
        eb[f] = v;
    }
    __syncthreads();

    // encoder: h0 = relu(x*enc_w + enc_b) + pos_row[i] + pos_col[j].
    // Both siblings write the FULL image in BOTH layouts (identical values ->
    // benign race; own copy guarantees own-visibility, so no startup gate).
    for (int p = tid; p < PIX; p += BDIM) {
        const int i = p / SS, j = p % SS;
        const float xv2 = ldsel(xv, (long)batch*PIX + p, isbf);
        float hv[DD];
        #pragma unroll
        for (int d = 0; d < DD; ++d)
            hv[d] = fmaxf(0.f, xv2*eb[d] + eb[8+d]) + eb[16 + i*8 + d] + eb[400 + j*8 + d];
        const float4 a = make_float4(hv[0], hv[1], hv[2], hv[3]);
        const float4 b = make_float4(hv[4], hv[5], hv[6], hv[7]);
        col0[p*2] = a;              col0[p*2+1] = b;            // [i][j][d]
        row0[(j*SS+i)*2] = a;       row0[(j*SS+i)*2+1] = b;     // [j][i][d]
    }

    // Layer l: reads parity l&1, writes parity (l+1)&1. WV(l)=l+1 posted after
    // the phase. Gate before layer l>0: opposite-axis sibling's WV(l-1) (own
    // region is self-written; double-buffer makes WV imply read-safety).
    #pragma unroll 1
    for (int l = 0; l < NL; ++l) {
        __syncthreads();                     // prior phase wb reads / encoder done
        if (tid == 0 && l > 0) {
            flag_wait(&flags[batch + (1-axis)*NBAT], (unsigned)l);
            __threadfence();                 // acquire: invalidate stale caches
        }
        const int la = l*2 + axis;
        for (int f = tid; f < 264; f += BDIM) {
            float v;
            if (f < 64)       v = ldsel(Wqv, la*64 + f, isbf);
            else if (f < 128) v = ldsel(Wkv, la*64 + f-64, isbf);
            else if (f < 192) v = ldsel(Wvv, la*64 + f-128, isbf);
            else if (f < 256) v = ldsel(Wov, la*64 + f-192, isbf);
            else              v = ldsel(bov, la*8 + f-256, isbf);
            wb[f] = v;
        }
        __syncthreads();                     // gate released + wb visible

        const int par = l & 1;
        float4* rin  = par ? row1 : row0;  float4* cin  = par ? col1 : col0;
        float4* rout = par ? row0 : row1;  float4* cout = par ? col0 : col1;
        const float4* own = axis ? (const float4*)cin : (const float4*)rin;
        const float4* oth = axis ? (const float4*)rin : (const float4*)cin;
        float4* gout = axis ? cout : rout;

        if (l == 0) attn_phase_f<1>(own, oth, gout, kvw, wb, wav, lane, tl);
        else        attn_phase_f<0>(own, oth, gout, kvw, wb, wav, lane, tl);
        __syncthreads();                     // drains each wave's global stores

        if (tid == 0) flag_post(&flags[bid], (unsigned)(l + 1));
    }

    if (axis != 0) return;

    // classifier (axis-0 block of each batch): final h lives in parity 0.
    if (tid == 0) {
        flag_wait(&flags[batch + NBAT], (unsigned)NL);
        __threadfence();
    }
    if (tid < NC) cb[tid] = ldsel(cls_bv, tid, isbf);
    __syncthreads();

    float pacc[NC] = {0.f,0.f,0.f,0.f,0.f,0.f,0.f};
    const float* cwf = (const float*)cls_wv;
    const __hip_bfloat16* cwb = (const __hip_bfloat16*)cls_wv;
    for (int p = tid; p < PIX; p += BDIM) {
        const int i = p / SS, j = p % SS;
        const float4 c0 = col0[p*2], c1 = col0[p*2+1];
        const float4 r0 = row0[(j*SS+i)*2], r1 = row0[(j*SS+i)*2+1];
        float mv =            fmaxf(0.f, c0.x + r0.x);
        mv = fmaxf(mv,        fmaxf(0.f, c0.y + r0.y));
        mv = fmaxf(mv,        fmaxf(0.f, c0.z + r0.z));
        mv = fmaxf(mv,        fmaxf(0.f, c0.w + r0.w));
        mv = fmaxf(mv,        fmaxf(0.f, c1.x + r1.x));
        mv = fmaxf(mv,        fmaxf(0.f, c1.y + r1.y));
        mv = fmaxf(mv,        fmaxf(0.f, c1.z + r1.z));
        mv = fmaxf(mv,        fmaxf(0.f, c1.w + r1.w));
        if (isbf) {
            #pragma unroll
            for (int c = 0; c < NC; ++c) pacc[c] += mv * __bfloat162float(cwb[c*PIX + p]);
        } else {
            #pragma unroll
            for (int c = 0; c < NC; ++c) pacc[c] += mv * cwf[c*PIX + p];
        }
    }
    #pragma unroll
    for (int c = 0; c < NC; ++c) {
        #pragma unroll
        for (int off = 32; off > 0; off >>= 1) pacc[c] += __shfl_down(pacc[c], off, 64);
    }
    if (lane == 0) {
        #pragma unroll
        for (int c = 0; c < NC; ++c) atomicAdd(&cb[c], pacc[c]);
    }
    __syncthreads();

    if (tid < NC) {
        float m = cb[0];
        #pragma unroll
        for (int c = 1; c < NC; ++c) m = fmaxf(m, cb[c]);
        float s = 0.f;
        #pragma unroll
        for (int c = 0; c < NC; ++c) s += exp2f((cb[c]-m) * 1.44269504089f);
        const float e = exp2f((cb[tid]-m) * 1.44269504089f);
        const float r = e / s;
        if (isbf) ((__hip_bfloat16*)outv)[batch*NC + tid] = __float2bfloat16(r);
        else      ((float*)outv)[batch*NC + tid] = r;
    }
}

extern "C" void kernel_launch(void* const* d_in, const int* in_sizes, int n_in,
                              void* d_out, int out_size, void* d_ws, size_t ws_size,
                              hipStream_t stream) {
    (void)in_sizes; (void)n_in; (void)ws_size; (void)out_size;
    hipFuncSetAttribute(reinterpret_cast<const void*>(&axial_u),
                        hipFuncAttributeMaxDynamicSharedMemorySize, SMEMF_BYTES);

    // zero epoch flags (stream-ordered, graph-capture-safe)
    hipMemsetAsync((char*)d_ws + FLAGS_OFF*4, 0, 256*sizeof(unsigned), stream);

    void* ins[12];
    for (int i = 0; i < 12; ++i) ins[i] = d_in[i];
    void* args[14];
    for (int i = 0; i < 12; ++i) args[i] = &ins[i];
    args[12] = &d_out;
    args[13] = &d_ws;     // needs 2*BUFSZ*4 + 256*4 ~= 37.75 MB (present since R5)

    // Single unconditional launch of the proven shape (R6: passed, 951us).
    // No ladder: a failed launch inside graph capture poisons the capture (R8).
    hipLaunchCooperativeKernel(reinterpret_cast<const void*>(&axial_u),
                               dim3(2*NBAT), dim3(BDIM), args,
                               (unsigned)SMEMF_BYTES, stream);
}

// Round 10
// 1207.256 us; speedup vs baseline: 1.2441x; 1.2441x over previous
//
#include <hip/hip_runtime.h>
#include <hip/hip_bf16.h>

// R10: eliminate dt[48] -- the register wall behind every failed round.
// R9 proved (512,1) caps at 128 VGPR with natural demand 124: ANY addition
// spills (FETCH 0.38->1.57GB). dt[48] exists only to avoid recomputing the
// QK dots (4 FMA each, operands still in LDS). Restructure per head:
//   pass1: dots with running max (fmax chain == tree, associative -> same m)
//   pass2: RECOMPUTE each dot (identical FMA order -> identical bits), fused
//          exp + sum + PV (identical accumulation orders -> bitwise output)
// Cost: +192 FMA + 96 LDS broadcasts per problem. Gain: ~48 VGPRs -> demand
// ~70-90 -> the 4-way split R7 proved admissible (512 blocks, 2 blocks/CU,
// 16 waves/CU) becomes register-safe (R8's crash zone was >=124 VGPR).
// Deterministic gate, no launch ladder (R8 lesson: a failed launch under
// graph capture poisons the capture): launch <4> iff numRegs<=112 AND
// occupancy>=2, else the proven <2> shape. Single unconditional launch.
#define BDIM 512
#define NBAT 128
#define SS   48
#define DD   8
#define HDIM 8
#define NL   8
#define NC   7
#define NWAV 8
#define PIX  (SS*SS)
#define RGN  (PIX*DD)            // one region: 18432 floats
#define GBAT (2*RGN)             // row+col regions per batch
#define BUFSZ ((size_t)NBAT*GBAT)      // one parity buffer (floats)
#define KVV  384
#define KVW  768
#define KVTOT (NWAV*KVW)
#define SMEMF_FLOATS (KVTOT + 264 + 784 + 8)
#define SMEMF_BYTES  (SMEMF_FLOATS*4)        // 28,800 B -> 2 blocks/CU LDS-wise
#define FLAGS_OFF ((size_t)2*BUFSZ)          // float offset of flags in d_ws

__device__ __forceinline__ float ldsel(const void* p, long i, bool bf) {
    return bf ? __bfloat162float(((const __hip_bfloat16*)p)[i])
              : ((const float*)p)[i];
}

__device__ __forceinline__ void flag_post(unsigned* f, unsigned v) {
    __threadfence();                                   // release: drain + L2 wb
    __hip_atomic_store(f, v, __ATOMIC_RELAXED, __HIP_MEMORY_SCOPE_AGENT);
}
__device__ __forceinline__ void flag_wait(unsigned* f, unsigned v) {
    while (__hip_atomic_load(f, __ATOMIC_RELAXED, __HIP_MEMORY_SCOPE_AGENT) < v)
        __builtin_amdgcn_s_sleep(1);
}

// Fused phase, register-lean body (no dt[48]).
// own/oth/gout as before: own = this orientation's region (self-written,
// coalesced (prob*SS+tl)); oth = opposite region ((tl*SS+prob), scattered,
// L2-absorbed). FIRST=1: layer 0 reads h0 as-is (no relu-add).
template <int NPROB, int FIRST>
__device__ __attribute__((noinline))
void attn_phase_f(const float4* __restrict__ gown, const float4* __restrict__ goth,
                  float4* __restrict__ gout, float* __restrict__ kvw,
                  const float* __restrict__ wb, int pbase, int wav, int lane, int tl)
{
    const float4* kv4 = reinterpret_cast<const float4*>(kvw);
    #pragma unroll 1
    for (int p = 0; p < NPROB/NWAV; ++p) {
        const int prob = pbase + wav + p*NWAV;
        const int aown = (prob*SS + tl)*2;

        float ht[DD];
        {
            const float4 o0 = gown[aown], o1 = gown[aown+1];
            if (FIRST) {
                ht[0]=o0.x; ht[1]=o0.y; ht[2]=o0.z; ht[3]=o0.w;
                ht[4]=o1.x; ht[5]=o1.y; ht[6]=o1.z; ht[7]=o1.w;
            } else {
                const int aoth = (tl*SS + prob)*2;
                const float4 t0 = goth[aoth], t1 = goth[aoth+1];
                ht[0]=fmaxf(0.f,o0.x+t0.x); ht[1]=fmaxf(0.f,o0.y+t0.y);
                ht[2]=fmaxf(0.f,o0.z+t0.z); ht[3]=fmaxf(0.f,o0.w+t0.w);
                ht[4]=fmaxf(0.f,o1.x+t1.x); ht[5]=fmaxf(0.f,o1.y+t1.y);
                ht[6]=fmaxf(0.f,o1.z+t1.z); ht[7]=fmaxf(0.f,o1.w+t1.w);
            }
        }

        // q/k/v projections; fold 0.5 (E^-0.5) * log2(e) into q for exp2.
        float q[HDIM];
        {
            float kk[HDIM], vv[HDIM];
            #pragma unroll
            for (int o = 0; o < HDIM; ++o) {
                float aq = 0.f, ak = 0.f, av = 0.f;
                #pragma unroll
                for (int d = 0; d < DD; ++d) {
                    aq += ht[d] * wb[o*8 + d];
                    ak += ht[d] * wb[64 + o*8 + d];
                    av += ht[d] * wb[128 + o*8 + d];
                }
                q[o] = aq * 0.72134752044f;  // 0.5 * log2(e)
                kk[o] = ak; vv[o] = av;
            }
            if (lane < SS) {   // lanes 48-63 would duplicate token 47: skip
                float4* kp = reinterpret_cast<float4*>(kvw + tl*8);
                kp[0] = make_float4(kk[0], kk[1], kk[2], kk[3]);
                kp[1] = make_float4(kk[4], kk[5], kk[6], kk[7]);
                float4* vp = reinterpret_cast<float4*>(kvw + KVV + tl*8);
                vp[0] = make_float4(vv[0], vv[1], vv[2], vv[3]);
                vp[1] = make_float4(vv[4], vv[5], vv[6], vv[7]);
            }
        }

        float ov[HDIM];
        #pragma unroll
        for (int hh = 0; hh < 2; ++hh) {
            // pass 1: dots with running max. fmax chain over the same set of
            // bitwise-identical dots == R6's tree (associative, no NaNs).
            float m;
            {
                const float4 kk4 = kv4[hh];              // j2 = 0
                float acc =  q[hh*4+0] * kk4.x;
                acc       += q[hh*4+1] * kk4.y;
                acc       += q[hh*4+2] * kk4.z;
                acc       += q[hh*4+3] * kk4.w;
                m = acc;
            }
            #pragma unroll 8
            for (int j2 = 1; j2 < SS; ++j2) {
                const float4 kk4 = kv4[j2*2 + hh];       // LDS same-addr broadcast
                float acc =  q[hh*4+0] * kk4.x;
                acc       += q[hh*4+1] * kk4.y;
                acc       += q[hh*4+2] * kk4.z;
                acc       += q[hh*4+3] * kk4.w;
                m = fmaxf(m, acc);
            }
            // pass 2: recompute dots (identical FMA order -> identical bits),
            // fused exp + serial sum + PV (same accumulation orders as R6).
            float s = 0.f;
            float o0 = 0.f, o1 = 0.f, o2 = 0.f, o3 = 0.f;
            #pragma unroll 8
            for (int j2 = 0; j2 < SS; ++j2) {
                const float4 kk4 = kv4[j2*2 + hh];
                float acc =  q[hh*4+0] * kk4.x;
                acc       += q[hh*4+1] * kk4.y;
                acc       += q[hh*4+2] * kk4.z;
                acc       += q[hh*4+3] * kk4.w;
                const float pv = exp2f(acc - m);
                s += pv;
                const float4 vv4 = kv4[KVV/4 + j2*2 + hh];
                o0 += pv * vv4.x;
                o1 += pv * vv4.y;
                o2 += pv * vv4.z;
                o3 += pv * vv4.w;
            }
            float rs = 1.f / s;
            ov[hh*4+0] = o0*rs; ov[hh*4+1] = o1*rs;
            ov[hh*4+2] = o2*rs; ov[hh*4+3] = o3*rs;
        }

        if (lane < SS) {
            float o8[DD];
            #pragma unroll
            for (int d = 0; d < DD; ++d) {
                float acc = wb[256 + d];
                #pragma unroll
                for (int o2 = 0; o2 < HDIM; ++o2) acc += ov[o2] * wb[192 + d*8 + o2];
                o8[d] = acc;
            }
            gout[aown]   = make_float4(o8[0], o8[1], o8[2], o8[3]);
            gout[aown+1] = make_float4(o8[4], o8[5], o8[6], o8[7]);
        }
    }
}

// NPART=4: 512 blocks (2 halves x 2 axes per batch, 3 problems/wave,
// 2 blocks/CU). NPART=2: 256 blocks (proven fallback). MINW=1 always: the
// only register-safe launch-bounds (MINW>=2 => 64-cap => spill, R1/R3/R7).
template <int NPART>
__global__ void __launch_bounds__(BDIM, 1)
axial_u(const void* xv, const void* enc_wv, const void* enc_bv,
        const void* pos_rowv, const void* pos_colv,
        const void* Wqv, const void* Wkv, const void* Wvv, const void* Wov,
        const void* bov, const void* cls_wv, const void* cls_bv,
        void* outv, void* wsv)
{
    // dtype sniff on x (wave-uniform): low bits of each dword are a plausible
    // bf16 exponent iff data is bf16-packed; random mantissa bits if fp32.
    const unsigned* xu = (const unsigned*)xv;
    int cnt = 0;
    #pragma unroll
    for (int t = 0; t < 32; ++t) {
        const unsigned w = xu[t];
        const int e = (w >> 7) & 0xff;
        cnt += (e > 100 && e < 150) ? 1 : 0;
    }
    const bool isbf = (cnt >= 20);

    float*    G     = (float*)wsv;
    unsigned* flags = (unsigned*)(G + FLAGS_OFF);

    extern __shared__ float smem[];
    float* kv = smem;              // per-wave k/v scratch [KVTOT]
    float* wb = kv + KVTOT;        // layer weights (own axis) [264]
    float* eb = wb + 264;          // enc params [784]
    float* cb = eb + 784;          // classifier logits [8]

    const int bid   = blockIdx.x;
    const int batch = bid & (NBAT-1);
    const int part  = bid >> 7;                         // 0..NPART-1
    const int axis  = (NPART == 4) ? (part >> 1) : part;
    const int pbase = (NPART == 4) ? ((part & 1) * (SS/2)) : 0;
    constexpr int NPROB = (NPART == 4) ? (SS/2) : SS;
    const int tid   = threadIdx.x;
    const int lane  = tid & 63;
    const int wav   = tid >> 6;
    const int tl    = lane < SS ? lane : SS-1;
    float* kvw = kv + wav*KVW;

    float* b0 = G + (size_t)batch*GBAT;                 // parity-0 buffer
    float* b1 = G + BUFSZ + (size_t)batch*GBAT;         // parity-1 buffer
    float4* row0 = (float4*)b0;  float4* col0 = (float4*)(b0 + RGN);
    float4* row1 = (float4*)b1;  float4* col1 = (float4*)(b1 + RGN);

    // stage encoder/pos params
    for (int f = tid; f < 784; f += BDIM) {
        float v;
        if (f < 8)        v = ldsel(enc_wv, f, isbf);
        else if (f < 16)  v = ldsel(enc_bv, f-8, isbf);
        else if (f < 400) v = ldsel(pos_rowv, f-16, isbf);
        else              v = ldsel(pos_colv, f-400, isbf);
        eb[f] = v;
    }
    __syncthreads();

    // encoder: h0 = relu(x*enc_w + enc_b) + pos_row[i] + pos_col[j].
    // Every sibling writes the FULL image in BOTH layouts (identical values ->
    // benign race; own copy guarantees own-visibility, so no startup gate).
    for (int p = tid; p < PIX; p += BDIM) {
        const int i = p / SS, j = p % SS;
        const float xv2 = ldsel(xv, (long)batch*PIX + p, isbf);
        float hv[DD];
        #pragma unroll
        for (int d = 0; d < DD; ++d)
            hv[d] = fmaxf(0.f, xv2*eb[d] + eb[8+d]) + eb[16 + i*8 + d] + eb[400 + j*8 + d];
        const float4 a = make_float4(hv[0], hv[1], hv[2], hv[3]);
        const float4 b = make_float4(hv[4], hv[5], hv[6], hv[7]);
        col0[p*2] = a;              col0[p*2+1] = b;            // [i][j][d]
        row0[(j*SS+i)*2] = a;       row0[(j*SS+i)*2+1] = b;     // [j][i][d]
    }

    // Layer l: reads parity l&1, writes parity (l+1)&1. WV(l)=l+1 posted after
    // the phase. Gate before layer l>0: opposite-axis siblings' WV(l-1) (own
    // region is self-written; double-buffer makes WV imply read-safety: the
    // data a block overwrites at layer l was last read by the opposite-axis
    // blocks during layer l-1, whose completion flag value l we wait on).
    #pragma unroll 1
    for (int l = 0; l < NL; ++l) {
        __syncthreads();                     // prior phase wb reads / encoder done
        if (tid == 0 && l > 0) {
            if (NPART == 4) {
                const int ob = axis ? 0 : 2;
                flag_wait(&flags[batch + ob*NBAT],     (unsigned)l);
                flag_wait(&flags[batch + (ob+1)*NBAT], (unsigned)l);
            } else {
                flag_wait(&flags[batch + (1-axis)*NBAT], (unsigned)l);
            }
            __threadfence();                 // acquire: invalidate stale caches
        }
        const int la = l*2 + axis;
        for (int f = tid; f < 264; f += BDIM) {
            float v;
            if (f < 64)       v = ldsel(Wqv, la*64 + f, isbf);
            else if (f < 128) v = ldsel(Wkv, la*64 + f-64, isbf);
            else if (f < 192) v = ldsel(Wvv, la*64 + f-128, isbf);
            else if (f < 256) v = ldsel(Wov, la*64 + f-192, isbf);
            else              v = ldsel(bov, la*8 + f-256, isbf);
            wb[f] = v;
        }
        __syncthreads();                     // gate released + wb visible

        const int par = l & 1;
        float4* rin  = par ? row1 : row0;  float4* cin  = par ? col1 : col0;
        float4* rout = par ? row0 : row1;  float4* cout = par ? col0 : col1;
        const float4* own = axis ? (const float4*)cin : (const float4*)rin;
        const float4* oth = axis ? (const float4*)rin : (const float4*)cin;
        float4* gout = axis ? cout : rout;

        if (l == 0) attn_phase_f<NPROB,1>(own, oth, gout, kvw, wb, pbase, wav, lane, tl);
        else        attn_phase_f<NPROB,0>(own, oth, gout, kvw, wb, pbase, wav, lane, tl);
        __syncthreads();                     // drains each wave's global stores

        if (tid == 0) flag_post(&flags[bid], (unsigned)(l + 1));
    }

    if (part != 0) return;

    // classifier (part 0 of each batch): final h lives in parity 0 (NL even).
    if (tid == 0) {
        #pragma unroll
        for (int qp = 1; qp < NPART; ++qp)
            flag_wait(&flags[batch + qp*NBAT], (unsigned)NL);
        __threadfence();
    }
    if (tid < NC) cb[tid] = ldsel(cls_bv, tid, isbf);
    __syncthreads();

    float pacc[NC] = {0.f,0.f,0.f,0.f,0.f,0.f,0.f};
    const float* cwf = (const float*)cls_wv;
    const __hip_bfloat16* cwb = (const __hip_bfloat16*)cls_wv;
    for (int p = tid; p < PIX; p += BDIM) {
        const int i = p / SS, j = p % SS;
        const float4 c0 = col0[p*2], c1 = col0[p*2+1];
        const float4 r0 = row0[(j*SS+i)*2], r1 = row0[(j*SS+i)*2+1];
        float mv =            fmaxf(0.f, c0.x + r0.x);
        mv = fmaxf(mv,        fmaxf(0.f, c0.y + r0.y));
        mv = fmaxf(mv,        fmaxf(0.f, c0.z + r0.z));
        mv = fmaxf(mv,        fmaxf(0.f, c0.w + r0.w));
        mv = fmaxf(mv,        fmaxf(0.f, c1.x + r1.x));
        mv = fmaxf(mv,        fmaxf(0.f, c1.y + r1.y));
        mv = fmaxf(mv,        fmaxf(0.f, c1.z + r1.z));
        mv = fmaxf(mv,        fmaxf(0.f, c1.w + r1.w));
        if (isbf) {
            #pragma unroll
            for (int c = 0; c < NC; ++c) pacc[c] += mv * __bfloat162float(cwb[c*PIX + p]);
        } else {
            #pragma unroll
            for (int c = 0; c < NC; ++c) pacc[c] += mv * cwf[c*PIX + p];
        }
    }
    #pragma unroll
    for (int c = 0; c < NC; ++c) {
        #pragma unroll
        for (int off = 32; off > 0; off >>= 1) pacc[c] += __shfl_down(pacc[c], off, 64);
    }
    if (lane == 0) {
        #pragma unroll
        for (int c = 0; c < NC; ++c) atomicAdd(&cb[c], pacc[c]);
    }
    __syncthreads();

    if (tid < NC) {
        float m = cb[0];
        #pragma unroll
        for (int c = 1; c < NC; ++c) m = fmaxf(m, cb[c]);
        float s = 0.f;
        #pragma unroll
        for (int c = 0; c < NC; ++c) s += exp2f((cb[c]-m) * 1.44269504089f);
        const float e = exp2f((cb[tid]-m) * 1.44269504089f);
        const float r = e / s;
        if (isbf) ((__hip_bfloat16*)outv)[batch*NC + tid] = __float2bfloat16(r);
        else      ((float*)outv)[batch*NC + tid] = r;
    }
}

extern "C" void kernel_launch(void* const* d_in, const int* in_sizes, int n_in,
                              void* d_out, int out_size, void* d_ws, size_t ws_size,
                              hipStream_t stream) {
    (void)in_sizes; (void)n_in; (void)ws_size; (void)out_size;
    hipFuncSetAttribute(reinterpret_cast<const void*>(&axial_u<4>),
                        hipFuncAttributeMaxDynamicSharedMemorySize, SMEMF_BYTES);
    hipFuncSetAttribute(reinterpret_cast<const void*>(&axial_u<2>),
                        hipFuncAttributeMaxDynamicSharedMemorySize, SMEMF_BYTES);

    // zero epoch flags (stream-ordered, graph-capture-safe)
    hipMemsetAsync((char*)d_ws + FLAGS_OFF*4, 0, 512*sizeof(unsigned), stream);

    void* ins[12];
    for (int i = 0; i < 12; ++i) ins[i] = d_in[i];
    void* args[14];
    for (int i = 0; i < 12; ++i) args[i] = &ins[i];
    args[12] = &d_out;
    args[13] = &d_ws;     // needs 2*BUFSZ*4 + 512*4 ~= 37.75 MB (present since R5)

    // Deterministic compile-fact gate (NO launch ladder -- R8 lesson: a failed
    // launch under graph capture poisons the capture). <4> requires the
    // register-lean body to have actually landed: numRegs <= 112 leaves margin
    // below the 128-granule (4 waves/SIMD = 2 blocks/CU) even with reserved
    // regs; occupancy API must independently confirm 2 blocks/CU.
    int occ = 0;
    hipOccupancyMaxActiveBlocksPerMultiprocessor(
        &occ, reinterpret_cast<const void*>(&axial_u<4>), BDIM, SMEMF_BYTES);
    hipFuncAttributes fa{};
    hipFuncGetAttributes(&fa, reinterpret_cast<const void*>(&axial_u<4>));

    if (occ >= 2 && fa.numRegs > 0 && fa.numRegs <= 112) {
        hipLaunchCooperativeKernel(reinterpret_cast<const void*>(&axial_u<4>),
                                   dim3(4*NBAT), dim3(BDIM), args,
                                   (unsigned)SMEMF_BYTES, stream);
    } else {
        hipLaunchCooperativeKernel(reinterpret_cast<const void*>(&axial_u<2>),
                                   dim3(2*NBAT), dim3(BDIM), args,
                                   (unsigned)SMEMF_BYTES, stream);
    }
}

// Round 11
// 986.279 us; speedup vs baseline: 1.5228x; 1.2241x over previous
//
#include <hip/hip_runtime.h>
#include <hip/hip_bf16.h>

// R11: same register environment, smaller block quantum. R10 proved the
// allocator fills the CAP (124 of 128) regardless of body, so occupancy at
// 512-thread blocks is stuck at 1 block/CU (2-block co-residency needs the
// impossible <=112 alloc). Empirical cap law across R1/R3/R7/R9/R10:
// cap = 512/(MINW * BDIM/128). So (256,2) == (512,1)'s proven environment
// (cap 128, alloc ~124, NO spill) but in a 4-wave block: 124 VGPR -> 4
// waves/SIMD tier -> 16 waves/CU -> FOUR 256-thread blocks/CU. Grid: NPART=8
// (2 axes x 4 quarters), 1024 blocks, 3 problems/wave. Fast dt[48] body
// RESTORED (R10's recompute cost +25% VALU: 951->1215us). Deterministic gate
// (no error-ladder -- R8: a failed launch under graph capture poisons the
// capture): <8,256,2> iff occ>=4 AND 100<=numRegs<=128 (floor detects a
// 64-cap squash => spill), else the proven <2,512,1> R6 shape (951us).
#define NBAT 128
#define SS   48
#define DD   8
#define HDIM 8
#define NL   8
#define NC   7
#define PIX  (SS*SS)
#define RGN  (PIX*DD)            // one region: 18432 floats
#define GBAT (2*RGN)             // row+col regions per batch
#define BUFSZ ((size_t)NBAT*GBAT)      // one parity buffer (floats)
#define KVV  384
#define KVW  768
#define FLAGS_OFF ((size_t)2*BUFSZ)    // float offset of flags in d_ws
#define SMEMB(TB) ((unsigned)(((TB)/64*KVW + 264 + 784 + 8)*4))

__device__ __forceinline__ float ldsel(const void* p, long i, bool bf) {
    return bf ? __bfloat162float(((const __hip_bfloat16*)p)[i])
              : ((const float*)p)[i];
}

__device__ __forceinline__ void flag_post(unsigned* f, unsigned v) {
    __threadfence();                                   // release: drain + L2 wb
    __hip_atomic_store(f, v, __ATOMIC_RELAXED, __HIP_MEMORY_SCOPE_AGENT);
}
__device__ __forceinline__ void flag_wait(unsigned* f, unsigned v) {
    while (__hip_atomic_load(f, __ATOMIC_RELAXED, __HIP_MEMORY_SCOPE_AGENT) < v)
        __builtin_amdgcn_s_sleep(1);
}

// Fused phase, fast dt[48] body (R6). own = this orientation's region
// (self-written, coalesced (prob*SS+tl)); oth = opposite region
// ((tl*SS+prob), scattered, L2-absorbed). FIRST=1: layer 0 reads h0 as-is.
template <int NPROB, int NWAVT, int FIRST>
__device__ __attribute__((noinline))
void attn_phase_f(const float4* __restrict__ gown, const float4* __restrict__ goth,
                  float4* __restrict__ gout, float* __restrict__ kvw,
                  const float* __restrict__ wb, int pbase, int wav, int lane, int tl)
{
    const float4* kv4 = reinterpret_cast<const float4*>(kvw);
    #pragma unroll 1
    for (int p = 0; p < NPROB/NWAVT; ++p) {
        const int prob = pbase + wav + p*NWAVT;
        const int aown = (prob*SS + tl)*2;

        float ht[DD];
        {
            const float4 o0 = gown[aown], o1 = gown[aown+1];
            if (FIRST) {
                ht[0]=o0.x; ht[1]=o0.y; ht[2]=o0.z; ht[3]=o0.w;
                ht[4]=o1.x; ht[5]=o1.y; ht[6]=o1.z; ht[7]=o1.w;
            } else {
                const int aoth = (tl*SS + prob)*2;
                const float4 t0 = goth[aoth], t1 = goth[aoth+1];
                ht[0]=fmaxf(0.f,o0.x+t0.x); ht[1]=fmaxf(0.f,o0.y+t0.y);
                ht[2]=fmaxf(0.f,o0.z+t0.z); ht[3]=fmaxf(0.f,o0.w+t0.w);
                ht[4]=fmaxf(0.f,o1.x+t1.x); ht[5]=fmaxf(0.f,o1.y+t1.y);
                ht[6]=fmaxf(0.f,o1.z+t1.z); ht[7]=fmaxf(0.f,o1.w+t1.w);
            }
        }

        // q/k/v projections; fold 0.5 (E^-0.5) * log2(e) into q for exp2.
        float q[HDIM];
        {
            float kk[HDIM], vv[HDIM];
            #pragma unroll
            for (int o = 0; o < HDIM; ++o) {
                float aq = 0.f, ak = 0.f, av = 0.f;
                #pragma unroll
                for (int d = 0; d < DD; ++d) {
                    aq += ht[d] * wb[o*8 + d];
                    ak += ht[d] * wb[64 + o*8 + d];
                    av += ht[d] * wb[128 + o*8 + d];
                }
                q[o] = aq * 0.72134752044f;  // 0.5 * log2(e)
                kk[o] = ak; vv[o] = av;
            }
            if (lane < SS) {   // lanes 48-63 would duplicate token 47: skip
                float4* kp = reinterpret_cast<float4*>(kvw + tl*8);
                kp[0] = make_float4(kk[0], kk[1], kk[2], kk[3]);
                kp[1] = make_float4(kk[4], kk[5], kk[6], kk[7]);
                float4* vp = reinterpret_cast<float4*>(kvw + KVV + tl*8);
                vp[0] = make_float4(vv[0], vv[1], vv[2], vv[3]);
                vp[1] = make_float4(vv[4], vv[5], vv[6], vv[7]);
            }
        }

        float ov[HDIM];
        #pragma unroll
        for (int hh = 0; hh < 2; ++hh) {
            float dt[SS];
            #pragma unroll
            for (int j2 = 0; j2 < SS; ++j2) {
                const float4 kk4 = kv4[j2*2 + hh];       // LDS same-addr broadcast
                float acc =  q[hh*4+0] * kk4.x;
                acc       += q[hh*4+1] * kk4.y;
                acc       += q[hh*4+2] * kk4.z;
                acc       += q[hh*4+3] * kk4.w;
                dt[j2] = acc;
            }
            // max tree (fmax exactly associative -> bitwise same as chain)
            float mt[24];
            #pragma unroll
            for (int t2 = 0; t2 < 24; ++t2) mt[t2] = fmaxf(dt[t2], dt[t2+24]);
            #pragma unroll
            for (int t2 = 0; t2 < 12; ++t2) mt[t2] = fmaxf(mt[t2], mt[t2+12]);
            #pragma unroll
            for (int t2 = 0; t2 < 6; ++t2)  mt[t2] = fmaxf(mt[t2], mt[t2+6]);
            #pragma unroll
            for (int t2 = 0; t2 < 3; ++t2)  mt[t2] = fmaxf(mt[t2], mt[t2+3]);
            const float m = fmaxf(fmaxf(mt[0], mt[1]), mt[2]);
            float s = 0.f;
            #pragma unroll
            for (int j2 = 0; j2 < SS; ++j2) {
                float pv = exp2f(dt[j2] - m);
                dt[j2] = pv; s += pv;
            }
            float o0 = 0.f, o1 = 0.f, o2 = 0.f, o3 = 0.f;
            #pragma unroll
            for (int j2 = 0; j2 < SS; ++j2) {
                const float4 vv4 = kv4[KVV/4 + j2*2 + hh];
                const float pv = dt[j2];
                o0 += pv * vv4.x;
                o1 += pv * vv4.y;
                o2 += pv * vv4.z;
                o3 += pv * vv4.w;
            }
            float rs = 1.f / s;
            ov[hh*4+0] = o0*rs; ov[hh*4+1] = o1*rs;
            ov[hh*4+2] = o2*rs; ov[hh*4+3] = o3*rs;
        }

        if (lane < SS) {
            float o8[DD];
            #pragma unroll
            for (int d = 0; d < DD; ++d) {
                float acc = wb[256 + d];
                #pragma unroll
                for (int o2 = 0; o2 < HDIM; ++o2) acc += ov[o2] * wb[192 + d*8 + o2];
                o8[d] = acc;
            }
            gout[aown]   = make_float4(o8[0], o8[1], o8[2], o8[3]);
            gout[aown+1] = make_float4(o8[4], o8[5], o8[6], o8[7]);
        }
    }
}

// NPART=8: 1024 blocks x 256 thr (2 axes x 4 quarters/batch, 4 blocks/CU).
// NPART=2: 256 blocks x 512 thr (proven R6 shape). Cap law: 512/(MW*TB/128).
template <int NPART, int TB, int MW>
__global__ void __launch_bounds__(TB, MW)
axial_k(const void* xv, const void* enc_wv, const void* enc_bv,
        const void* pos_rowv, const void* pos_colv,
        const void* Wqv, const void* Wkv, const void* Wvv, const void* Wov,
        const void* bov, const void* cls_wv, const void* cls_bv,
        void* outv, void* wsv)
{
    constexpr int NWAVT = TB/64;
    constexpr int NPROB = (NPART == 8) ? (SS/4) : SS;

    // dtype sniff on x (wave-uniform): low bits of each dword are a plausible
    // bf16 exponent iff data is bf16-packed; random mantissa bits if fp32.
    const unsigned* xu = (const unsigned*)xv;
    int cnt = 0;
    #pragma unroll
    for (int t = 0; t < 32; ++t) {
        const unsigned w = xu[t];
        const int e = (w >> 7) & 0xff;
        cnt += (e > 100 && e < 150) ? 1 : 0;
    }
    const bool isbf = (cnt >= 20);

    float*    G     = (float*)wsv;
    unsigned* flags = (unsigned*)(G + FLAGS_OFF);

    extern __shared__ float smem[];
    float* kv = smem;              // per-wave k/v scratch [NWAVT*KVW]
    float* wb = kv + NWAVT*KVW;    // layer weights (own axis) [264]
    float* eb = wb + 264;          // enc params [784]
    float* cb = eb + 784;          // classifier logits [8]

    const int bid   = blockIdx.x;
    const int batch = bid & (NBAT-1);
    const int part  = bid >> 7;                         // 0..NPART-1
    const int axis  = (NPART == 8) ? (part >> 2) : part;
    const int pbase = (NPART == 8) ? ((part & 3) * NPROB) : 0;
    const int tid   = threadIdx.x;
    const int lane  = tid & 63;
    const int wav   = tid >> 6;
    const int tl    = lane < SS ? lane : SS-1;
    float* kvw = kv + wav*KVW;

    float* b0 = G + (size_t)batch*GBAT;                 // parity-0 buffer
    float* b1 = G + BUFSZ + (size_t)batch*GBAT;         // parity-1 buffer
    float4* row0 = (float4*)b0;  float4* col0 = (float4*)(b0 + RGN);
    float4* row1 = (float4*)b1;  float4* col1 = (float4*)(b1 + RGN);

    // stage encoder/pos params
    for (int f = tid; f < 784; f += TB) {
        float v;
        if (f < 8)        v = ldsel(enc_wv, f, isbf);
        else if (f < 16)  v = ldsel(enc_bv, f-8, isbf);
        else if (f < 400) v = ldsel(pos_rowv, f-16, isbf);
        else              v = ldsel(pos_colv, f-400, isbf);
        eb[f] = v;
    }
    __syncthreads();

    // encoder: h0 = relu(x*enc_w + enc_b) + pos_row[i] + pos_col[j].
    // Each block writes ONLY the quarter it reads at layer 0, in its own
    // orientation (no cross-block h0 dependency; parity-0 regions are fully
    // rewritten by layer 7 before the classifier reads them).
    {
        float4* own0 = axis ? col0 : row0;
        for (int idx = tid; idx < NPROB*SS; idx += TB) {
            const int prob = pbase + idx/SS, tok = idx%SS;
            const int i = axis ? prob : tok, j = axis ? tok : prob;
            const float xv2 = ldsel(xv, (long)batch*PIX + i*SS + j, isbf);
            float hv[DD];
            #pragma unroll
            for (int d = 0; d < DD; ++d)
                hv[d] = fmaxf(0.f, xv2*eb[d] + eb[8+d]) + eb[16 + i*8 + d] + eb[400 + j*8 + d];
            own0[(prob*SS+tok)*2]   = make_float4(hv[0], hv[1], hv[2], hv[3]);
            own0[(prob*SS+tok)*2+1] = make_float4(hv[4], hv[5], hv[6], hv[7]);
        }
    }

    // Layer l: reads parity l&1, writes parity (l+1)&1. WV(l)=l+1 posted
    // after the phase. Gate before layer l>0: ALL opposite-axis parts' WV(l-1)
    // (own-region reads are quarter-local and self-written; double-buffer
    // makes WV imply read-safety: the buffer overwritten at layer l was last
    // read by opposite-axis parts during layer l-1, whose flag value l gates).
    #pragma unroll 1
    for (int l = 0; l < NL; ++l) {
        __syncthreads();                     // prior phase wb reads / encoder done
        if (tid == 0 && l > 0) {
            if (NPART == 8) {
                const int ob = axis ? 0 : 4;
                #pragma unroll
                for (int qq = 0; qq < 4; ++qq)
                    flag_wait(&flags[batch + (ob+qq)*NBAT], (unsigned)l);
            } else {
                flag_wait(&flags[batch + (1-axis)*NBAT], (unsigned)l);
            }
            __threadfence();                 // acquire: invalidate stale caches
        }
        const int la = l*2 + axis;
        for (int f = tid; f < 264; f += TB) {
            float v;
            if (f < 64)       v = ldsel(Wqv, la*64 + f, isbf);
            else if (f < 128) v = ldsel(Wkv, la*64 + f-64, isbf);
            else if (f < 192) v = ldsel(Wvv, la*64 + f-128, isbf);
            else if (f < 256) v = ldsel(Wov, la*64 + f-192, isbf);
            else              v = ldsel(bov, la*8 + f-256, isbf);
            wb[f] = v;
        }
        __syncthreads();                     // gate released + wb visible

        const int par = l & 1;
        float4* rin  = par ? row1 : row0;  float4* cin  = par ? col1 : col0;
        float4* rout = par ? row0 : row1;  float4* cout = par ? col0 : col1;
        const float4* own = axis ? (const float4*)cin : (const float4*)rin;
        const float4* oth = axis ? (const float4*)rin : (const float4*)cin;
        float4* gout = axis ? cout : rout;

        if (l == 0) attn_phase_f<NPROB,NWAVT,1>(own, oth, gout, kvw, wb, pbase, wav, lane, tl);
        else        attn_phase_f<NPROB,NWAVT,0>(own, oth, gout, kvw, wb, pbase, wav, lane, tl);
        __syncthreads();                     // drains each wave's global stores

        if (tid == 0) flag_post(&flags[bid], (unsigned)(l + 1));
    }

    if (part != 0) return;

    // classifier (part 0 of each batch): final h lives in parity 0 (NL even).
    if (tid == 0) {
        #pragma unroll
        for (int qp = 1; qp < NPART; ++qp)
            flag_wait(&flags[batch + qp*NBAT], (unsigned)NL);
        __threadfence();
    }
    if (tid < NC) cb[tid] = ldsel(cls_bv, tid, isbf);
    __syncthreads();

    float pacc[NC] = {0.f,0.f,0.f,0.f,0.f,0.f,0.f};
    const float* cwf = (const float*)cls_wv;
    const __hip_bfloat16* cwb = (const __hip_bfloat16*)cls_wv;
    for (int p = tid; p < PIX; p += TB) {
        const int i = p / SS, j = p % SS;
        const float4 c0 = col0[p*2], c1 = col0[p*2+1];
        const float4 r0 = row0[(j*SS+i)*2], r1 = row0[(j*SS+i)*2+1];
        float mv =            fmaxf(0.f, c0.x + r0.x);
        mv = fmaxf(mv,        fmaxf(0.f, c0.y + r0.y));
        mv = fmaxf(mv,        fmaxf(0.f, c0.z + r0.z));
        mv = fmaxf(mv,        fmaxf(0.f, c0.w + r0.w));
        mv = fmaxf(mv,        fmaxf(0.f, c1.x + r1.x));
        mv = fmaxf(mv,        fmaxf(0.f, c1.y + r1.y));
        mv = fmaxf(mv,        fmaxf(0.f, c1.z + r1.z));
        mv = fmaxf(mv,        fmaxf(0.f, c1.w + r1.w));
        if (isbf) {
            #pragma unroll
            for (int c = 0; c < NC; ++c) pacc[c] += mv * __bfloat162float(cwb[c*PIX + p]);
        } else {
            #pragma unroll
            for (int c = 0; c < NC; ++c) pacc[c] += mv * cwf[c*PIX + p];
        }
    }
    #pragma unroll
    for (int c = 0; c < NC; ++c) {
        #pragma unroll
        for (int off = 32; off > 0; off >>= 1) pacc[c] += __shfl_down(pacc[c], off, 64);
    }
    if (lane == 0) {
        #pragma unroll
        for (int c = 0; c < NC; ++c) atomicAdd(&cb[c], pacc[c]);
    }
    __syncthreads();

    if (tid < NC) {
        float m = cb[0];
        #pragma unroll
        for (int c = 1; c < NC; ++c) m = fmaxf(m, cb[c]);
        float s = 0.f;
        #pragma unroll
        for (int c = 0; c < NC; ++c) s += exp2f((cb[c]-m) * 1.44269504089f);
        const float e = exp2f((cb[tid]-m) * 1.44269504089f);
        const float r = e / s;
        if (isbf) ((__hip_bfloat16*)outv)[batch*NC + tid] = __float2bfloat16(r);
        else      ((float*)outv)[batch*NC + tid] = r;
    }
}

extern "C" void kernel_launch(void* const* d_in, const int* in_sizes, int n_in,
                              void* d_out, int out_size, void* d_ws, size_t ws_size,
                              hipStream_t stream) {
    (void)in_sizes; (void)n_in; (void)ws_size; (void)out_size;
    hipFuncSetAttribute(reinterpret_cast<const void*>(&axial_k<8,256,2>),
                        hipFuncAttributeMaxDynamicSharedMemorySize, SMEMB(256));
    hipFuncSetAttribute(reinterpret_cast<const void*>(&axial_k<2,512,1>),
                        hipFuncAttributeMaxDynamicSharedMemorySize, SMEMB(512));

    // zero epoch flags (stream-ordered, graph-capture-safe)
    hipMemsetAsync((char*)d_ws + FLAGS_OFF*4, 0, 1024*sizeof(unsigned), stream);

    void* ins[12];
    for (int i = 0; i < 12; ++i) ins[i] = d_in[i];
    void* args[14];
    for (int i = 0; i < 12; ++i) args[i] = &ins[i];
    args[12] = &d_out;
    args[13] = &d_ws;     // needs 2*BUFSZ*4 + 4KB ~= 37.75 MB (present since R5)

    // Deterministic gate, single launch (no error-ladder: R8 lesson).
    // 8-way requires: occupancy API confirming 4 blocks/CU, AND numRegs in
    // [100,128] (floor detects a 64-cap squash => dt[48] spill => the R7
    // failure mode; ceiling is the 4-waves/SIMD tier boundary).
    int occ = 0;
    hipOccupancyMaxActiveBlocksPerMultiprocessor(
        &occ, reinterpret_cast<const void*>(&axial_k<8,256,2>), 256, SMEMB(256));
    hipFuncAttributes fa{};
    hipFuncGetAttributes(&fa, reinterpret_cast<const void*>(&axial_k<8,256,2>));

    if (occ >= 4 && fa.numRegs >= 100 && fa.numRegs <= 128) {
        hipLaunchCooperativeKernel(reinterpret_cast<const void*>(&axial_k<8,256,2>),
                                   dim3(8*NBAT), dim3(256), args,
                                   SMEMB(256), stream);
    } else {
        hipLaunchCooperativeKernel(reinterpret_cast<const void*>(&axial_k<2,512,1>),
                                   dim3(2*NBAT), dim3(512), args,
                                   SMEMB(512), stream);
    }
}